// Round 3
// baseline (258.102 us; speedup 1.0000x reference)
//
#include <hip/hip_runtime.h>
#include <hip/hip_bf16.h>
#include <stdint.h>

typedef __bf16 bf16_t;
typedef __attribute__((ext_vector_type(8))) __bf16 bf16x8;
typedef __attribute__((ext_vector_type(4))) __bf16 bf16x4;
typedef __attribute__((ext_vector_type(4))) float f32x4;

static constexpr int T_SEQ = 2048;
static constexpr int HID   = 2048;
static constexpr int NHEAD = 32;
static constexpr int NKVH  = 8;
static constexpr int HDIM  = 64;
static constexpr int QKVD  = 3072;   // 64*(32+16)

__device__ inline f32x4 mfma16(bf16x8 a, bf16x8 b, f32x4 c) {
    return __builtin_amdgcn_mfma_f32_16x16x32_bf16(a, b, c, 0, 0, 0);
}

__device__ inline void load_lds16(const bf16_t* g, bf16_t* l) {
    __builtin_amdgcn_global_load_lds(
        (const __attribute__((address_space(1))) void*)g,
        (__attribute__((address_space(3))) void*)l, 16, 0, 0);
}

// ---------------- prep: weight transposes + RMSNorm (one dispatch) ----------------
// blocks [0,1536): Wq transpose; [1536,2560): Wo transpose; [2560,4608): rmsnorm rows.
__global__ __launch_bounds__(256) void prep_kernel(const float* __restrict__ Wq,
                                                   const float* __restrict__ Wo,
                                                   bf16_t* __restrict__ Tq,
                                                   bf16_t* __restrict__ To,
                                                   const float* __restrict__ x,
                                                   const float* __restrict__ scale,
                                                   bf16_t* __restrict__ normed) {
    __shared__ float tile[64 * 65];
    int b = blockIdx.x;
    const int t = threadIdx.x;
    if (b < 2560) {
        const float* in; bf16_t* outw; int NN, KK, bx, by;
        if (b < 1536) { in = Wq; outw = Tq; NN = QKVD; KK = HID; bx = b % 48; by = b / 48; }
        else { b -= 1536; in = Wo; outw = To; NN = HID; KK = HID; bx = b % 32; by = b / 32; }
        const int c4 = (t & 15) * 4;
#pragma unroll
        for (int i = 0; i < 4; ++i) {
            int r = (t >> 4) + i * 16;
            float4 v = *(const float4*)(in + (size_t)(by*64 + r) * NN + bx*64 + c4);
            tile[r*65 + c4 + 0] = v.x; tile[r*65 + c4 + 1] = v.y;
            tile[r*65 + c4 + 2] = v.z; tile[r*65 + c4 + 3] = v.w;
        }
        __syncthreads();
        const int kc = t & 7;
#pragma unroll
        for (int i = 0; i < 2; ++i) {
            int n = (t >> 3) + i * 32;
            bf16x8 o;
#pragma unroll
            for (int j = 0; j < 8; ++j) o[j] = (bf16_t)tile[(kc*8 + j)*65 + n];
            *(bf16x8*)(outw + (size_t)(bx*64 + n) * KK + by*64 + kc*8) = o;
        }
    } else {
        int row = b - 2560;
        const float4* x4 = (const float4*)(x + (size_t)row * HID);
        const float4* s4 = (const float4*)scale;
        float4 v0 = x4[t], v1 = x4[t + 256];
        float ss = v0.x*v0.x + v0.y*v0.y + v0.z*v0.z + v0.w*v0.w
                 + v1.x*v1.x + v1.y*v1.y + v1.z*v1.z + v1.w*v1.w;
#pragma unroll
        for (int off = 32; off > 0; off >>= 1) ss += __shfl_down(ss, off);
        if ((t & 63) == 0) tile[t >> 6] = ss;
        __syncthreads();
        float total = tile[0] + tile[1] + tile[2] + tile[3];
        float inv = rsqrtf(total * (1.0f / HID) + 1e-5f);
        float4 sc0 = s4[t], sc1 = s4[t + 256];
        bf16_t* outr = normed + (size_t)row * HID;
        bf16x4 o0, o1;
        o0.x = (bf16_t)(v0.x*inv*sc0.x); o0.y = (bf16_t)(v0.y*inv*sc0.y);
        o0.z = (bf16_t)(v0.z*inv*sc0.z); o0.w = (bf16_t)(v0.w*inv*sc0.w);
        o1.x = (bf16_t)(v1.x*inv*sc1.x); o1.y = (bf16_t)(v1.y*inv*sc1.y);
        o1.z = (bf16_t)(v1.z*inv*sc1.z); o1.w = (bf16_t)(v1.w*inv*sc1.w);
        *(bf16x4*)(outr + 4*t)        = o0;
        *(bf16x4*)(outr + 1024 + 4*t) = o1;
    }
}

// ---------------- split-K GEMM, 128x128 tile, pipelined BK=32 steps ------------------
__global__ __launch_bounds__(256) void gemm_splitk(const bf16_t* __restrict__ A,
                                                   const bf16_t* __restrict__ Bt,
                                                   bf16_t* __restrict__ Cpart,
                                                   int M, int N, int K) {
    __shared__ __align__(16) bf16_t Asm[3 * 128 * 32];   // 24 KB
    __shared__ __align__(16) bf16_t Bsm[3 * 128 * 32];   // 24 KB
    const int tid = threadIdx.x;
    const int bm = blockIdx.y * 128, bn = blockIdx.x * 128;
    const int kh = K >> 1;
    const int kb = blockIdx.z * kh;
    const int lane = tid & 63, wave = tid >> 6;
    const int wm = (wave & 1) * 64, wn = (wave >> 1) * 64;
    const int lm = lane & 15, quad = lane >> 4;

    f32x4 acc[4][4];
#pragma unroll
    for (int i = 0; i < 4; ++i)
#pragma unroll
        for (int j = 0; j < 4; ++j) acc[i][j] = (f32x4){0.f, 0.f, 0.f, 0.f};

    const int cid0 = tid, cid1 = tid + 256;
    const int r0 = cid0 >> 2, c0 = (cid0 & 3) ^ ((r0 >> 1) & 3);
    const int r1 = cid1 >> 2, c1 = (cid1 & 3) ^ ((r1 >> 1) & 3);
    const bf16_t* Ab = A  + (size_t)bm * K + kb;
    const bf16_t* Bb = Bt + (size_t)bn * K + kb;
    const size_t ga0 = (size_t)r0 * K + c0 * 8;
    const size_t ga1 = (size_t)r1 * K + c1 * 8;
    const int swz = (quad ^ ((lm >> 1) & 3)) * 8;
    const int ldso = wave * 512;

    const int nsteps = kh >> 5;   // K=2048, splitK=2 -> 32 steps

#define STAGE(buf, k0) do {                               \
        bf16_t* la_ = &Asm[(buf) * 4096];                 \
        bf16_t* lb_ = &Bsm[(buf) * 4096];                 \
        load_lds16(Ab + ga0 + (k0), la_ + ldso);          \
        load_lds16(Ab + ga1 + (k0), la_ + 2048 + ldso);   \
        load_lds16(Bb + ga0 + (k0), lb_ + ldso);          \
        load_lds16(Bb + ga1 + (k0), lb_ + 2048 + ldso);   \
    } while (0)

    STAGE(0, 0);
    STAGE(1, 32);

    int cur = 0, nxt = 2;
    for (int t = 0; t < nsteps; ++t) {
        if (t + 1 < nsteps) asm volatile("s_waitcnt vmcnt(4)" ::: "memory");
        else                asm volatile("s_waitcnt vmcnt(0)" ::: "memory");
        __builtin_amdgcn_s_barrier();
        __builtin_amdgcn_sched_barrier(0);
        if (t + 2 < nsteps) STAGE(nxt, (t + 2) * 32);

        const bf16_t* __restrict__ Abase = &Asm[cur * 4096];
        const bf16_t* __restrict__ Bbase = &Bsm[cur * 4096];
        bf16x8 af[4], bfr[4];
#pragma unroll
        for (int i = 0; i < 4; ++i)
            af[i]  = *(const bf16x8*)&Abase[(wm + i*16 + lm)*32 + swz];
#pragma unroll
        for (int j = 0; j < 4; ++j)
            bfr[j] = *(const bf16x8*)&Bbase[(wn + j*16 + lm)*32 + swz];
#pragma unroll
        for (int i = 0; i < 4; ++i)
#pragma unroll
            for (int j = 0; j < 4; ++j) acc[i][j] = mfma16(af[i], bfr[j], acc[i][j]);

        cur = (cur == 2) ? 0 : cur + 1;
        nxt = (nxt == 2) ? 0 : nxt + 1;
    }
#undef STAGE

    bf16_t* Cp = Cpart + (size_t)blockIdx.z * M * N;
#pragma unroll
    for (int i = 0; i < 4; ++i) {
        int gr = bm + wm + i*16 + quad*4;
#pragma unroll
        for (int j = 0; j < 4; ++j) {
            int gc = bn + wn + j*16 + lm;
#pragma unroll
            for (int r = 0; r < 4; ++r)
                Cp[(size_t)(gr + r)*N + gc] = (bf16_t)acc[i][j][r];
        }
    }
}

// ---------------- combine out-proj partials + bias + residual ----------------
__global__ __launch_bounds__(256) void combine_out(const bf16_t* __restrict__ p0,
                                                   const bf16_t* __restrict__ p1,
                                                   const float* __restrict__ bias,
                                                   const float* __restrict__ x,
                                                   float* __restrict__ out) {
    const int n4 = T_SEQ * HID / 4;
    for (int i4 = blockIdx.x * 256 + threadIdx.x; i4 < n4; i4 += gridDim.x * 256) {
        bf16x4 a = *(const bf16x4*)(p0 + (size_t)i4 * 4);
        bf16x4 b = *(const bf16x4*)(p1 + (size_t)i4 * 4);
        float4 xv = *(const float4*)(x + (size_t)i4 * 4);
        int col4 = (i4 * 4) & (HID - 1);
        float4 bi = *(const float4*)(bias + col4);
        float4 o;
        o.x = (float)a.x + (float)b.x + bi.x + xv.x;
        o.y = (float)a.y + (float)b.y + bi.y + xv.y;
        o.z = (float)a.z + (float)b.z + bi.z + xv.z;
        o.w = (float)a.w + (float)b.w + bi.w + xv.w;
        *(float4*)(out + (size_t)i4 * 4) = o;
    }
}

// ---------------- fused attention: combine QKV partials + bias + RoPE inline ------------
// Grid (T/64, NHEAD) = 1024 blocks, 256 thr (4 waves) — round-0 parallelism (3 blocks/CU,
// 12 waves/CU) with the combine+bias+RoPE fusion kept inline. Wave w: q-rows w*16..+16.
// K fragments built per wave in registers (redundant across waves/blocks; L2 absorbs —
// occupancy is the binding constraint, per round-2 post-mortem). Ws rows wave-private;
// single __syncthreads() (for Vt).
__global__ __launch_bounds__(256, 3) void attn_fused(const bf16_t* __restrict__ qp0,
                                                     const bf16_t* __restrict__ qp1,
                                                     const float* __restrict__ qkvb,
                                                     const float* __restrict__ cost,
                                                     const float* __restrict__ sint,
                                                     const float* __restrict__ sinks,
                                                     bf16_t* __restrict__ attnb) {
    __shared__ __align__(16) bf16_t Vt[64 * 200];    // V^T [d][k], 25.6 KB
    __shared__ __align__(16) bf16_t Ws[64 * 200];    // weights, rows wave-private, 25.6 KB

    const int tid = threadIdx.x;
    const int qt = blockIdx.x, h = blockIdx.y;
    const int nkv = h >> 2;
    const int qs = qt * 64;

    // ---- V^T staging from partials (+bias), conflict-free packed-pair writes ----
    {
        const int off = (tid >> 5) * 8;          // d-group 0..56
        const float* vb = qkvb + 2560 + nkv * 64;
#pragma unroll
        for (int it = 0; it < 3; ++it) {
            int j2 = (tid & 31) + 32 * it;       // k-pair index 0..95
            int kg0 = qs - 128 + 2 * j2;     if (kg0 < 0) kg0 = 0;
            int kg1 = qs - 128 + 2 * j2 + 1; if (kg1 < 0) kg1 = 0;
            const size_t o0 = (size_t)kg0 * QKVD + 2560 + nkv * 64 + off;
            const size_t o1 = (size_t)kg1 * QKVD + 2560 + nkv * 64 + off;
            bf16x8 a0 = *(const bf16x8*)(qp0 + o0), b0 = *(const bf16x8*)(qp1 + o0);
            bf16x8 a1 = *(const bf16x8*)(qp0 + o1), b1 = *(const bf16x8*)(qp1 + o1);
#pragma unroll
            for (int r = 0; r < 8; ++r) {
                union { uint u; bf16_t e[2]; } p;
                p.e[0] = (bf16_t)((float)a0[r] + (float)b0[r] + vb[off + r]);
                p.e[1] = (bf16_t)((float)a1[r] + (float)b1[r] + vb[off + r]);
                *(uint*)&Vt[(off + r) * 200 + 2 * j2] = p.u;
            }
        }
    }

    const int lane = tid & 63, wave = tid >> 6;
    const int lm = lane & 15, quad = lane >> 4;
    const int w16 = wave * 16;

    // ---- K-window fragments in registers: combine + bias + rope ----
    int krow[12];
#pragma unroll
    for (int jt = 0; jt < 12; ++jt) {
        int kg = qs - 128 + jt * 16 + lm;
        krow[jt] = kg < 0 ? 0 : kg;
    }
    bf16x8 kf0[12], kf1[12];
    {
        const float* kb = qkvb + 2048 + nkv * 64;
#pragma unroll
        for (int jt = 0; jt < 12; ++jt) {
            const size_t ko = (size_t)krow[jt] * QKVD + 2048 + nkv * 64 + quad * 8;
            bf16x8 a0 = *(const bf16x8*)(qp0 + ko);
            bf16x8 a1 = *(const bf16x8*)(qp0 + ko + 32);
            bf16x8 b0 = *(const bf16x8*)(qp1 + ko);
            bf16x8 b1 = *(const bf16x8*)(qp1 + ko + 32);
            const float* c = cost + (size_t)krow[jt] * 32 + quad * 8;
            const float* s = sint + (size_t)krow[jt] * 32 + quad * 8;
#pragma unroll
            for (int j = 0; j < 8; ++j) {
                float x1 = (float)a0[j] + (float)b0[j] + kb[quad * 8 + j];
                float x2 = (float)a1[j] + (float)b1[j] + kb[quad * 8 + j + 32];
                float cc = c[j], ssn = s[j];
                kf0[jt][j] = (bf16_t)(x1 * cc - x2 * ssn);
                kf1[jt][j] = (bf16_t)(x2 * cc + x1 * ssn);
            }
        }
    }

    // ---- Q fragment: combine + bias + rope on load ----
    bf16x8 aq0, aq1;
    {
        const int qrow = qs + w16 + lm;
        const size_t qo = (size_t)qrow * QKVD + h * 64 + quad * 8;
        bf16x8 a0 = *(const bf16x8*)(qp0 + qo);
        bf16x8 a1 = *(const bf16x8*)(qp0 + qo + 32);
        bf16x8 b0 = *(const bf16x8*)(qp1 + qo);
        bf16x8 b1 = *(const bf16x8*)(qp1 + qo + 32);
        const float* qb = qkvb + h * 64;
        const float* c = cost + (size_t)qrow * 32 + quad * 8;
        const float* s = sint + (size_t)qrow * 32 + quad * 8;
#pragma unroll
        for (int j = 0; j < 8; ++j) {
            float x1 = (float)a0[j] + (float)b0[j] + qb[quad * 8 + j];
            float x2 = (float)a1[j] + (float)b1[j] + qb[quad * 8 + j + 32];
            float cc = c[j], ssn = s[j];
            aq0[j] = (bf16_t)(x1 * cc - x2 * ssn);
            aq1[j] = (bf16_t)(x2 * cc + x1 * ssn);
        }
    }

    __syncthreads();   // Vt ready; Ws rows wave-private so no further barriers

    f32x4 S[12];
#pragma unroll
    for (int jt = 0; jt < 12; ++jt) S[jt] = (f32x4){0.f, 0.f, 0.f, 0.f};
#pragma unroll
    for (int jt = 0; jt < 12; ++jt) S[jt] = mfma16(aq0, kf0[jt], S[jt]);
#pragma unroll
    for (int jt = 0; jt < 12; ++jt) S[jt] = mfma16(aq1, kf1[jt], S[jt]);

    const float sink = sinks[h];
#pragma unroll
    for (int reg = 0; reg < 4; ++reg) {
        const int qg = qs + w16 + quad * 4 + reg;
        float mx = -1e30f;
#pragma unroll
        for (int jt = 0; jt < 12; ++jt) {
            int kg = qs - 128 + jt * 16 + lm;
            float sv = S[jt][reg] * 0.125f;
            bool valid = (kg >= 0) && (kg <= qg) && (qg - kg <= 128);
            sv = valid ? sv : -1e30f;
            S[jt][reg] = sv;
            mx = fmaxf(mx, sv);
        }
#pragma unroll
        for (int off = 1; off < 16; off <<= 1) mx = fmaxf(mx, __shfl_xor(mx, off));
        float M = fmaxf(mx, sink);
        float sum = 0.f;
#pragma unroll
        for (int jt = 0; jt < 12; ++jt) {
            float e = __expf(S[jt][reg] - M);
            S[jt][reg] = e; sum += e;
        }
#pragma unroll
        for (int off = 1; off < 16; off <<= 1) sum += __shfl_xor(sum, off);
        float rden = 1.f / (sum + __expf(sink - M));
#pragma unroll
        for (int jt = 0; jt < 12; ++jt)
            Ws[(w16 + quad * 4 + reg) * 200 + jt * 16 + lm] =
                (bf16_t)(S[jt][reg] * rden);
    }
    // no barrier: this wave reads only its own Ws rows (per-wave LDS ordering)

    f32x4 O[4];
#pragma unroll
    for (int nt = 0; nt < 4; ++nt) O[nt] = (f32x4){0.f, 0.f, 0.f, 0.f};
#pragma unroll
    for (int ks = 0; ks < 6; ++ks) {
        bf16x8 aw = *(const bf16x8*)&Ws[(w16 + lm) * 200 + ks * 32 + quad * 8];
#pragma unroll
        for (int nt = 0; nt < 4; ++nt) {
            bf16x8 bv = *(const bf16x8*)&Vt[(nt * 16 + lm) * 200 + ks * 32 + quad * 8];
            O[nt] = mfma16(aw, bv, O[nt]);
        }
    }
#pragma unroll
    for (int nt = 0; nt < 4; ++nt)
#pragma unroll
        for (int reg = 0; reg < 4; ++reg)
            attnb[(size_t)(qs + w16 + quad * 4 + reg) * HID + h * HDIM + nt * 16 + lm] =
                (bf16_t)(O[nt][reg]);
}

// ---------------- launch ----------------
extern "C" void kernel_launch(void* const* d_in, const int* in_sizes, int n_in,
                              void* d_out, int out_size, void* d_ws, size_t ws_size,
                              hipStream_t stream) {
    (void)in_sizes; (void)n_in; (void)out_size; (void)ws_size;
    const float* x          = (const float*)d_in[0];
    const float* scale      = (const float*)d_in[1];
    const float* sinks      = (const float*)d_in[2];
    const float* qkv_kernel = (const float*)d_in[3];
    const float* qkv_bias   = (const float*)d_in[4];
    const float* out_kernel = (const float*)d_in[5];
    const float* out_bias   = (const float*)d_in[6];
    const float* cos_t      = (const float*)d_in[7];
    const float* sin_t      = (const float*)d_in[8];
    float* out = (float*)d_out;

    // ws plan (64 MiB, aliasing by liveness):
    //   [ 0, 8)   Wt_out  bf16 [2048][2048]  (alive all run)
    //   [ 8,20)   Wt_qkv  bf16 [3072][2048]  (dead after QKV gemm)
    //   [ 8,16)   attnb   bf16 [T][2048]     (aliases Wt_qkv)
    //   [20,28)   normed  bf16 [T][2048]
    //   [28,52)   qkvp    bf16 [2][T][3072]  (dead after attn)
    //   [28,44)   outp    bf16 [2][T][2048]  (aliases qkvp; written after attn)
    char* ws = (char*)d_ws;
    const size_t MiB = 1048576;
    bf16_t* Wt_out = (bf16_t*)(ws);
    bf16_t* Wt_qkv = (bf16_t*)(ws + 8*MiB);
    bf16_t* attnb  = (bf16_t*)(ws + 8*MiB);
    bf16_t* normed = (bf16_t*)(ws + 20*MiB);
    bf16_t* qkvp   = (bf16_t*)(ws + 28*MiB);
    bf16_t* outp   = (bf16_t*)(ws + 28*MiB);

    prep_kernel<<<4608, 256, 0, stream>>>(qkv_kernel, out_kernel, Wt_qkv, Wt_out,
                                          x, scale, normed);
    gemm_splitk<<<dim3(QKVD/128, T_SEQ/128, 2), 256, 0, stream>>>(normed, Wt_qkv, qkvp,
                                                                  T_SEQ, QKVD, HID);
    attn_fused<<<dim3(T_SEQ/64, NHEAD), 256, 0, stream>>>(qkvp, qkvp + (size_t)T_SEQ*QKVD,
                                                          qkv_bias, cos_t, sin_t, sinks,
                                                          attnb);
    gemm_splitk<<<dim3(HID/128, T_SEQ/128, 2), 256, 0, stream>>>(attnb, Wt_out, outp,
                                                                 T_SEQ, HID, HID);
    combine_out<<<2048, 256, 0, stream>>>(outp, outp + (size_t)T_SEQ*HID, out_bias, x, out);
}

// Round 4
// 219.308 us; speedup vs baseline: 1.1769x; 1.1769x over previous
//
#include <hip/hip_runtime.h>
#include <hip/hip_bf16.h>
#include <stdint.h>

typedef __bf16 bf16_t;
typedef __attribute__((ext_vector_type(8))) __bf16 bf16x8;
typedef __attribute__((ext_vector_type(4))) __bf16 bf16x4;
typedef __attribute__((ext_vector_type(4))) float f32x4;

static constexpr int T_SEQ = 2048;
static constexpr int HID   = 2048;
static constexpr int NHEAD = 32;
static constexpr int NKVH  = 8;
static constexpr int HDIM  = 64;
static constexpr int QKVD  = 3072;   // 64*(32+16)

__device__ inline f32x4 mfma16(bf16x8 a, bf16x8 b, f32x4 c) {
    return __builtin_amdgcn_mfma_f32_16x16x32_bf16(a, b, c, 0, 0, 0);
}

__device__ inline void load_lds16(const bf16_t* g, bf16_t* l) {
    __builtin_amdgcn_global_load_lds(
        (const __attribute__((address_space(1))) void*)g,
        (__attribute__((address_space(3))) void*)l, 16, 0, 0);
}

// ---------------- prep: weight transposes + RMSNorm (one dispatch) ----------------
// blocks [0,1536): Wq transpose; [1536,2560): Wo transpose; [2560,4608): rmsnorm rows.
__global__ __launch_bounds__(256) void prep_kernel(const float* __restrict__ Wq,
                                                   const float* __restrict__ Wo,
                                                   bf16_t* __restrict__ Tq,
                                                   bf16_t* __restrict__ To,
                                                   const float* __restrict__ x,
                                                   const float* __restrict__ scale,
                                                   bf16_t* __restrict__ normed) {
    __shared__ float tile[64 * 65];
    int b = blockIdx.x;
    const int t = threadIdx.x;
    if (b < 2560) {
        const float* in; bf16_t* outw; int NN, KK, bx, by;
        if (b < 1536) { in = Wq; outw = Tq; NN = QKVD; KK = HID; bx = b % 48; by = b / 48; }
        else { b -= 1536; in = Wo; outw = To; NN = HID; KK = HID; bx = b % 32; by = b / 32; }
        const int c4 = (t & 15) * 4;
#pragma unroll
        for (int i = 0; i < 4; ++i) {
            int r = (t >> 4) + i * 16;
            float4 v = *(const float4*)(in + (size_t)(by*64 + r) * NN + bx*64 + c4);
            tile[r*65 + c4 + 0] = v.x; tile[r*65 + c4 + 1] = v.y;
            tile[r*65 + c4 + 2] = v.z; tile[r*65 + c4 + 3] = v.w;
        }
        __syncthreads();
        const int kc = t & 7;
#pragma unroll
        for (int i = 0; i < 2; ++i) {
            int n = (t >> 3) + i * 32;
            bf16x8 o;
#pragma unroll
            for (int j = 0; j < 8; ++j) o[j] = (bf16_t)tile[(kc*8 + j)*65 + n];
            *(bf16x8*)(outw + (size_t)(bx*64 + n) * KK + by*64 + kc*8) = o;
        }
    } else {
        int row = b - 2560;
        const float4* x4 = (const float4*)(x + (size_t)row * HID);
        const float4* s4 = (const float4*)scale;
        float4 v0 = x4[t], v1 = x4[t + 256];
        float ss = v0.x*v0.x + v0.y*v0.y + v0.z*v0.z + v0.w*v0.w
                 + v1.x*v1.x + v1.y*v1.y + v1.z*v1.z + v1.w*v1.w;
#pragma unroll
        for (int off = 32; off > 0; off >>= 1) ss += __shfl_down(ss, off);
        if ((t & 63) == 0) tile[t >> 6] = ss;
        __syncthreads();
        float total = tile[0] + tile[1] + tile[2] + tile[3];
        float inv = rsqrtf(total * (1.0f / HID) + 1e-5f);
        float4 sc0 = s4[t], sc1 = s4[t + 256];
        bf16_t* outr = normed + (size_t)row * HID;
        bf16x4 o0, o1;
        o0.x = (bf16_t)(v0.x*inv*sc0.x); o0.y = (bf16_t)(v0.y*inv*sc0.y);
        o0.z = (bf16_t)(v0.z*inv*sc0.z); o0.w = (bf16_t)(v0.w*inv*sc0.w);
        o1.x = (bf16_t)(v1.x*inv*sc1.x); o1.y = (bf16_t)(v1.y*inv*sc1.y);
        o1.z = (bf16_t)(v1.z*inv*sc1.z); o1.w = (bf16_t)(v1.w*inv*sc1.w);
        *(bf16x4*)(outr + 4*t)        = o0;
        *(bf16x4*)(outr + 1024 + 4*t) = o1;
    }
}

// ---------------- split-K GEMM, 128x128 tile, BK=64 (round-0 verified core) ----------
// Each 32-k sub-tile uses the verified conflict-free geometry: LDS chunk j holds
// global chunk (r=j>>2, c=(j&3)^((r>>1)&3)); frag read offset (quad^((lm>>1)&3))*8.
__global__ __launch_bounds__(256) void gemm_splitk(const bf16_t* __restrict__ A,
                                                   const bf16_t* __restrict__ Bt,
                                                   bf16_t* __restrict__ Cpart,
                                                   int M, int N, int K) {
    __shared__ __align__(16) bf16_t Asm[2 * 128 * 32];   // 16 KB
    __shared__ __align__(16) bf16_t Bsm[2 * 128 * 32];   // 16 KB
    const int tid = threadIdx.x;
    const int bm = blockIdx.y * 128, bn = blockIdx.x * 128;
    const int kh = K >> 1;
    const int kb = blockIdx.z * kh;
    const int lane = tid & 63, wave = tid >> 6;
    const int wm = (wave & 1) * 64, wn = (wave >> 1) * 64;
    const int lm = lane & 15, quad = lane >> 4;

    f32x4 acc[4][4];
#pragma unroll
    for (int i = 0; i < 4; ++i)
#pragma unroll
        for (int j = 0; j < 4; ++j) acc[i][j] = (f32x4){0.f, 0.f, 0.f, 0.f};

    const int cid0 = tid, cid1 = tid + 256;
    const int r0 = cid0 >> 2, c0 = (cid0 & 3) ^ ((r0 >> 1) & 3);
    const int r1 = cid1 >> 2, c1 = (cid1 & 3) ^ ((r1 >> 1) & 3);
    const bf16_t* Ab = A  + (size_t)bm * K + kb;
    const bf16_t* Bb = Bt + (size_t)bn * K + kb;
    const size_t ga0 = (size_t)r0 * K + c0 * 8;
    const size_t ga1 = (size_t)r1 * K + c1 * 8;
    bf16_t* ldsA0a = &Asm[wave * 512];
    bf16_t* ldsA0b = &Asm[2048 + wave * 512];
    bf16_t* ldsA1a = &Asm[4096 + wave * 512];
    bf16_t* ldsA1b = &Asm[4096 + 2048 + wave * 512];
    bf16_t* ldsB0a = &Bsm[wave * 512];
    bf16_t* ldsB0b = &Bsm[2048 + wave * 512];
    bf16_t* ldsB1a = &Bsm[4096 + wave * 512];
    bf16_t* ldsB1b = &Bsm[4096 + 2048 + wave * 512];
    const int swz = (quad ^ ((lm >> 1) & 3)) * 8;

    for (int k0 = 0; k0 < kh; k0 += 64) {
        load_lds16(Ab + ga0 + k0,      ldsA0a);
        load_lds16(Ab + ga1 + k0,      ldsA0b);
        load_lds16(Ab + ga0 + k0 + 32, ldsA1a);
        load_lds16(Ab + ga1 + k0 + 32, ldsA1b);
        load_lds16(Bb + ga0 + k0,      ldsB0a);
        load_lds16(Bb + ga1 + k0,      ldsB0b);
        load_lds16(Bb + ga0 + k0 + 32, ldsB1a);
        load_lds16(Bb + ga1 + k0 + 32, ldsB1b);
        __syncthreads();
#pragma unroll
        for (int ks = 0; ks < 2; ++ks) {
            bf16x8 af[4], bfr[4];
#pragma unroll
            for (int i = 0; i < 4; ++i)
                af[i]  = *(const bf16x8*)&Asm[ks*4096 + (wm + i*16 + lm)*32 + swz];
#pragma unroll
            for (int j = 0; j < 4; ++j)
                bfr[j] = *(const bf16x8*)&Bsm[ks*4096 + (wn + j*16 + lm)*32 + swz];
#pragma unroll
            for (int i = 0; i < 4; ++i)
#pragma unroll
                for (int j = 0; j < 4; ++j) acc[i][j] = mfma16(af[i], bfr[j], acc[i][j]);
        }
        __syncthreads();
    }

    bf16_t* Cp = Cpart + (size_t)blockIdx.z * M * N;
#pragma unroll
    for (int i = 0; i < 4; ++i) {
        int gr = bm + wm + i*16 + quad*4;
#pragma unroll
        for (int j = 0; j < 4; ++j) {
            int gc = bn + wn + j*16 + lm;
#pragma unroll
            for (int r = 0; r < 4; ++r)
                Cp[(size_t)(gr + r)*N + gc] = (bf16_t)acc[i][j][r];
        }
    }
}

// ---------------- combine partials + bias + rope (vectorized), scatter to Q/K/V ----------
__global__ __launch_bounds__(192) void rope_split(const bf16_t* __restrict__ qp0,
                                                  const bf16_t* __restrict__ qp1,
                                                  const float* __restrict__ qbias,
                                                  const float* __restrict__ cost,
                                                  const float* __restrict__ sint,
                                                  bf16_t* __restrict__ Qb,
                                                  bf16_t* __restrict__ Kb,
                                                  bf16_t* __restrict__ Vb) {
    const int t = blockIdx.x;
    const int hr = threadIdx.x >> 2, p0 = (threadIdx.x & 3) * 8;
    const bf16_t* r0 = qp0 + (size_t)t * QKVD + hr * 64;
    const bf16_t* r1 = qp1 + (size_t)t * QKVD + hr * 64;
    bf16x8 a1 = *(const bf16x8*)(r0 + p0);
    bf16x8 a2 = *(const bf16x8*)(r0 + p0 + 32);
    bf16x8 b1 = *(const bf16x8*)(r1 + p0);
    bf16x8 b2 = *(const bf16x8*)(r1 + p0 + 32);
    const float* qb = qbias + hr * 64;
    float qbl[8], qbh[8];
    *(float4*)&qbl[0] = *(const float4*)(qb + p0);
    *(float4*)&qbl[4] = *(const float4*)(qb + p0 + 4);
    *(float4*)&qbh[0] = *(const float4*)(qb + p0 + 32);
    *(float4*)&qbh[4] = *(const float4*)(qb + p0 + 36);
    float x1[8], x2[8];
#pragma unroll
    for (int j = 0; j < 8; ++j) {
        x1[j] = (float)a1[j] + (float)b1[j] + qbl[j];
        x2[j] = (float)a2[j] + (float)b2[j] + qbh[j];
    }
    bf16x8 w1, w2;
    if (hr < 40) {
        float cc[8], ssn[8];
        *(float4*)&cc[0]  = *(const float4*)(cost + (size_t)t * 32 + p0);
        *(float4*)&cc[4]  = *(const float4*)(cost + (size_t)t * 32 + p0 + 4);
        *(float4*)&ssn[0] = *(const float4*)(sint + (size_t)t * 32 + p0);
        *(float4*)&ssn[4] = *(const float4*)(sint + (size_t)t * 32 + p0 + 4);
#pragma unroll
        for (int j = 0; j < 8; ++j) {
            w1[j] = (bf16_t)(x1[j]*cc[j] - x2[j]*ssn[j]);
            w2[j] = (bf16_t)(x2[j]*cc[j] + x1[j]*ssn[j]);
        }
    } else {
#pragma unroll
        for (int j = 0; j < 8; ++j) { w1[j] = (bf16_t)x1[j]; w2[j] = (bf16_t)x2[j]; }
    }
    bf16_t* dst;
    if (hr < 32)      dst = Qb + ((size_t)t*NHEAD + hr)      * HDIM;
    else if (hr < 40) dst = Kb + ((size_t)t*NKVH + (hr-32))  * HDIM;
    else              dst = Vb + ((size_t)t*NKVH + (hr-40))  * HDIM;
    *(bf16x8*)(dst + p0)      = w1;
    *(bf16x8*)(dst + p0 + 32) = w2;
}

// ---------------- combine out-proj partials + bias + residual ----------------
__global__ __launch_bounds__(256) void combine_out(const bf16_t* __restrict__ p0,
                                                   const bf16_t* __restrict__ p1,
                                                   const float* __restrict__ bias,
                                                   const float* __restrict__ x,
                                                   float* __restrict__ out) {
    const int n4 = T_SEQ * HID / 4;
    for (int i4 = blockIdx.x * 256 + threadIdx.x; i4 < n4; i4 += gridDim.x * 256) {
        bf16x4 a = *(const bf16x4*)(p0 + (size_t)i4 * 4);
        bf16x4 b = *(const bf16x4*)(p1 + (size_t)i4 * 4);
        float4 xv = *(const float4*)(x + (size_t)i4 * 4);
        int col4 = (i4 * 4) & (HID - 1);
        float4 bi = *(const float4*)(bias + col4);
        float4 o;
        o.x = (float)a.x + (float)b.x + bi.x + xv.x;
        o.y = (float)a.y + (float)b.y + bi.y + xv.y;
        o.z = (float)a.z + (float)b.z + bi.z + xv.z;
        o.w = (float)a.w + (float)b.w + bi.w + xv.w;
        *(float4*)(out + (size_t)i4 * 4) = o;
    }
}

// ---------------- attention: direct global Q/K frags, one barrier, conflict-free Vt ------
// Round-0 verified structure + T5 setprio around the two MFMA clusters (m191 regime:
// multi-wave blocks, waves free-running after the single barrier).
__global__ __launch_bounds__(256) void attn_kernel(const bf16_t* __restrict__ Qb,
                                                   const bf16_t* __restrict__ Kb,
                                                   const bf16_t* __restrict__ Vb,
                                                   const float* __restrict__ sinks,
                                                   bf16_t* __restrict__ attnb) {
    __shared__ __align__(16) bf16_t Vt[64 * 200];
    __shared__ __align__(16) bf16_t Ws[64 * 200];

    const int tid = threadIdx.x;
    const int qt = blockIdx.x, h = blockIdx.y;
    const int qs = qt * 64;
    const int nkv = h >> 2;

    // V^T staging, conflict-free: lanes 0..31 of each half write 32 consecutive words.
    {
        const int off = (tid >> 5) * 8;
#pragma unroll
        for (int it = 0; it < 3; ++it) {
            int j2 = (tid & 31) + 32 * it;
            int kg0 = qs - 128 + 2*j2;     if (kg0 < 0) kg0 = 0;
            int kg1 = qs - 128 + 2*j2 + 1; if (kg1 < 0) kg1 = 0;
            union { uint4 u; bf16_t e[8]; } v0, v1;
            v0.u = *(const uint4*)(Vb + ((size_t)kg0*NKVH + nkv)*HDIM + off);
            v1.u = *(const uint4*)(Vb + ((size_t)kg1*NKVH + nkv)*HDIM + off);
#pragma unroll
            for (int r = 0; r < 8; ++r) {
                union { uint u; bf16_t e[2]; } p;
                p.e[0] = v0.e[r]; p.e[1] = v1.e[r];
                *(uint*)&Vt[(off + r)*200 + 2*j2] = p.u;
            }
        }
    }

    const int lane = tid & 63, wave = tid >> 6;
    const int lm = lane & 15, quad = lane >> 4;
    const int w16 = wave * 16;

    f32x4 S[12];
#pragma unroll
    for (int jt = 0; jt < 12; ++jt) S[jt] = (f32x4){0.f, 0.f, 0.f, 0.f};
    const bf16_t* Qrow = Qb + ((size_t)(qs + w16 + lm)*NHEAD + h)*HDIM + quad*8;
    int krow[12];
#pragma unroll
    for (int jt = 0; jt < 12; ++jt) {
        int kg = qs - 128 + jt*16 + lm;
        krow[jt] = kg < 0 ? 0 : kg;
    }
    __builtin_amdgcn_s_setprio(1);
#pragma unroll
    for (int ks = 0; ks < 2; ++ks) {
        bf16x8 aq = *(const bf16x8*)(Qrow + ks*32);
#pragma unroll
        for (int jt = 0; jt < 12; ++jt) {
            bf16x8 bk = *(const bf16x8*)(Kb + ((size_t)krow[jt]*NKVH + nkv)*HDIM + ks*32 + quad*8);
            S[jt] = mfma16(aq, bk, S[jt]);
        }
    }
    __builtin_amdgcn_s_setprio(0);

    const float sink = sinks[h];
#pragma unroll
    for (int reg = 0; reg < 4; ++reg) {
        const int qg = qs + w16 + quad*4 + reg;
        float mx = -1e30f;
#pragma unroll
        for (int jt = 0; jt < 12; ++jt) {
            int kg = qs - 128 + jt*16 + lm;
            float sv = S[jt][reg] * 0.125f;
            bool valid = (kg >= 0) && (kg <= qg) && (qg - kg <= 128);
            sv = valid ? sv : -1e30f;
            S[jt][reg] = sv;
            mx = fmaxf(mx, sv);
        }
#pragma unroll
        for (int off = 1; off < 16; off <<= 1) mx = fmaxf(mx, __shfl_xor(mx, off));
        float M = fmaxf(mx, sink);
        float sum = 0.f;
#pragma unroll
        for (int jt = 0; jt < 12; ++jt) {
            float e = __expf(S[jt][reg] - M);
            S[jt][reg] = e; sum += e;
        }
#pragma unroll
        for (int off = 1; off < 16; off <<= 1) sum += __shfl_xor(sum, off);
        float rden = 1.f / (sum + __expf(sink - M));
#pragma unroll
        for (int jt = 0; jt < 12; ++jt)
            Ws[(w16 + quad*4 + reg)*200 + jt*16 + lm] = (bf16_t)(S[jt][reg] * rden);
    }
    __syncthreads();

    f32x4 O[4];
#pragma unroll
    for (int nt = 0; nt < 4; ++nt) O[nt] = (f32x4){0.f, 0.f, 0.f, 0.f};
    __builtin_amdgcn_s_setprio(1);
#pragma unroll
    for (int ks = 0; ks < 6; ++ks) {
        bf16x8 aw = *(const bf16x8*)&Ws[(w16 + lm)*200 + ks*32 + quad*8];
#pragma unroll
        for (int nt = 0; nt < 4; ++nt) {
            bf16x8 bv = *(const bf16x8*)&Vt[(nt*16 + lm)*200 + ks*32 + quad*8];
            O[nt] = mfma16(aw, bv, O[nt]);
        }
    }
    __builtin_amdgcn_s_setprio(0);
#pragma unroll
    for (int nt = 0; nt < 4; ++nt)
#pragma unroll
        for (int reg = 0; reg < 4; ++reg)
            attnb[(size_t)(qs + w16 + quad*4 + reg)*HID + h*HDIM + nt*16 + lm] =
                (bf16_t)(O[nt][reg]);
}

// ---------------- launch ----------------
extern "C" void kernel_launch(void* const* d_in, const int* in_sizes, int n_in,
                              void* d_out, int out_size, void* d_ws, size_t ws_size,
                              hipStream_t stream) {
    (void)in_sizes; (void)n_in; (void)out_size; (void)ws_size;
    const float* x          = (const float*)d_in[0];
    const float* scale      = (const float*)d_in[1];
    const float* sinks      = (const float*)d_in[2];
    const float* qkv_kernel = (const float*)d_in[3];
    const float* qkv_bias   = (const float*)d_in[4];
    const float* out_kernel = (const float*)d_in[5];
    const float* out_bias   = (const float*)d_in[6];
    const float* cos_t      = (const float*)d_in[7];
    const float* sin_t      = (const float*)d_in[8];
    float* out = (float*)d_out;

    // ws plan (64 MiB, aliasing by liveness):
    //   [ 0, 8)   Wt_out  bf16 [2048][2048]  (alive all run)
    //   [ 8,20)   Wt_qkv  bf16 [3072][2048]  (dead after QKV gemm)
    //   [ 8,16)   attnb   bf16 [T][2048]     (aliases Wt_qkv)
    //   [20,28)   normed  bf16 [T][2048]
    //   [28,52)   qkvp    bf16 [2][T][3072]  (dead after rope)
    //   [28,44)   outp    bf16 [2][T][2048]  (aliases qkvp)
    //   [52,64)   Qb/Kb/Vb bf16
    char* ws = (char*)d_ws;
    const size_t MiB = 1048576;
    bf16_t* Wt_out = (bf16_t*)(ws);
    bf16_t* Wt_qkv = (bf16_t*)(ws + 8*MiB);
    bf16_t* attnb  = (bf16_t*)(ws + 8*MiB);
    bf16_t* normed = (bf16_t*)(ws + 20*MiB);
    bf16_t* qkvp   = (bf16_t*)(ws + 28*MiB);
    bf16_t* outp   = (bf16_t*)(ws + 28*MiB);
    bf16_t* Qb     = (bf16_t*)(ws + 52*MiB);
    bf16_t* Kb     = (bf16_t*)(ws + 60*MiB);
    bf16_t* Vb     = (bf16_t*)(ws + 62*MiB);

    prep_kernel<<<4608, 256, 0, stream>>>(qkv_kernel, out_kernel, Wt_qkv, Wt_out,
                                          x, scale, normed);
    gemm_splitk<<<dim3(QKVD/128, T_SEQ/128, 2), 256, 0, stream>>>(normed, Wt_qkv, qkvp,
                                                                  T_SEQ, QKVD, HID);
    rope_split<<<T_SEQ, 192, 0, stream>>>(qkvp, qkvp + (size_t)T_SEQ*QKVD, qkv_bias,
                                          cos_t, sin_t, Qb, Kb, Vb);
    attn_kernel<<<dim3(T_SEQ/64, NHEAD), 256, 0, stream>>>(Qb, Kb, Vb, sinks, attnb);
    gemm_splitk<<<dim3(HID/128, T_SEQ/128, 2), 256, 0, stream>>>(attnb, Wt_out, outp,
                                                                 T_SEQ, HID, HID);
    combine_out<<<2048, 256, 0, stream>>>(outp, outp + (size_t)T_SEQ*HID, out_bias, x, out);
}